// Round 1
// baseline (385.920 us; speedup 1.0000x reference)
//
#include <hip/hip_runtime.h>

#define BLOCK 256

__global__ __launch_bounds__(BLOCK) void chamfer_min_kernel(
    const float* __restrict__ xyz1, const float* __restrict__ xyz2,
    float* __restrict__ out, int N, int M,
    float scale1, float scale2)
{
    const int dir = blockIdx.y;   // 0: xyz1 -> xyz2, 1: xyz2 -> xyz1
    const int b   = blockIdx.z;

    const float* __restrict__ P = (dir == 0) ? xyz1 : xyz2;
    const float* __restrict__ Q = (dir == 0) ? xyz2 : xyz1;
    const int n  = (dir == 0) ? N : M;     // query count
    const int mm = (dir == 0) ? M : N;     // search count
    const float scale = (dir == 0) ? scale1 : scale2;

    const int i = blockIdx.x * BLOCK + threadIdx.x;   // grid sized exactly: i < n

    // this thread's query point
    const float* p = P + ((size_t)b * n + i) * 3;
    const float x = p[0], y = p[1], z = p[2];

    // batch's search set: addresses are block-uniform -> scalar loads (SGPRs)
    const float* __restrict__ q = Q + (size_t)b * mm * 3;

    float m0 = 3.4e38f, m1 = 3.4e38f, m2 = 3.4e38f, m3 = 3.4e38f;

    #pragma unroll 2
    for (int j = 0; j < mm; j += 4) {
        const float* qj = q + 3 * j;
        {
            float dx = x - qj[0], dy = y - qj[1], dz = z - qj[2];
            float d = dx * dx + dy * dy + dz * dz;
            m0 = fminf(m0, d);
        }
        {
            float dx = x - qj[3], dy = y - qj[4], dz = z - qj[5];
            float d = dx * dx + dy * dy + dz * dz;
            m1 = fminf(m1, d);
        }
        {
            float dx = x - qj[6], dy = y - qj[7], dz = z - qj[8];
            float d = dx * dx + dy * dy + dz * dz;
            m2 = fminf(m2, d);
        }
        {
            float dx = x - qj[9], dy = y - qj[10], dz = z - qj[11];
            float d = dx * dx + dy * dy + dz * dz;
            m3 = fminf(m3, d);
        }
    }

    float v = fminf(fminf(m0, m1), fminf(m2, m3)) * scale;

    // wave (64-lane) reduce sum
    #pragma unroll
    for (int off = 32; off > 0; off >>= 1)
        v += __shfl_down(v, off, 64);

    __shared__ float ssum[BLOCK / 64];
    const int lane = threadIdx.x & 63;
    const int wave = threadIdx.x >> 6;
    if (lane == 0) ssum[wave] = v;
    __syncthreads();

    if (threadIdx.x == 0) {
        float t = 0.f;
        #pragma unroll
        for (int w = 0; w < BLOCK / 64; ++w) t += ssum[w];
        atomicAdd(out, t);
    }
}

extern "C" void kernel_launch(void* const* d_in, const int* in_sizes, int n_in,
                              void* d_out, int out_size, void* d_ws, size_t ws_size,
                              hipStream_t stream) {
    const float* xyz1 = (const float*)d_in[0];
    const float* xyz2 = (const float*)d_in[1];
    float* out = (float*)d_out;

    const int B = 4;
    const int N = in_sizes[0] / (B * 3);   // 8192
    const int M = in_sizes[1] / (B * 3);   // 8192

    // d_out is poisoned to 0xAA before every timed launch — zero it.
    hipMemsetAsync(out, 0, sizeof(float) * out_size, stream);

    const float scale1 = 1.0f / ((float)B * (float)N);
    const float scale2 = 1.0f / ((float)B * (float)M);

    dim3 grid(N / BLOCK, 2, B);
    dim3 block(BLOCK);
    chamfer_min_kernel<<<grid, block, 0, stream>>>(xyz1, xyz2, out, N, M, scale1, scale2);
}

// Round 2
// 148.173 us; speedup vs baseline: 2.6045x; 2.6045x over previous
//
#include <hip/hip_runtime.h>

#define BLOCK 256
#define JC 8          // j-chunks per (dir, b)

// Phase 0: pack search sets as (-2x, -2y, -2z, |q|^2).
// Layout in ws: pack[0 .. B*M)       = packed xyz2  (search set for dir 0)
//               pack[B*M .. B*M+B*N) = packed xyz1  (search set for dir 1)
__global__ __launch_bounds__(BLOCK) void pack_kernel(
    const float* __restrict__ xyz1, const float* __restrict__ xyz2,
    float4* __restrict__ pack, int BN, int BM)
{
    int t = blockIdx.x * BLOCK + threadIdx.x;
    if (t < BM) {
        float x = xyz2[3 * t], y = xyz2[3 * t + 1], z = xyz2[3 * t + 2];
        pack[t] = make_float4(-2.f * x, -2.f * y, -2.f * z, x * x + y * y + z * z);
    } else if (t < BM + BN) {
        int u = t - BM;
        float x = xyz1[3 * u], y = xyz1[3 * u + 1], z = xyz1[3 * u + 2];
        pack[t] = make_float4(-2.f * x, -2.f * y, -2.f * z, x * x + y * y + z * z);
    }
}

// Phase 1: per (dir, b, query, chunk) partial min, combined via atomicMin on
// int bits (values >= ~0; positive-float int compare preserves order).
__global__ __launch_bounds__(BLOCK) void chamfer_min_kernel(
    const float* __restrict__ xyz1, const float* __restrict__ xyz2,
    const float4* __restrict__ pack, int* __restrict__ minws,
    int N, int M, int B)
{
    const int z   = blockIdx.z;        // dir*B + b
    const int dir = z >> 2;            // B == 4
    const int b   = z & 3;

    const float* __restrict__ P = (dir == 0) ? xyz1 : xyz2;  // queries
    const int n  = (dir == 0) ? N : M;                       // query count
    const int mm = (dir == 0) ? M : N;                       // search count

    const int i = blockIdx.x * BLOCK + threadIdx.x;          // query index (< n)

    const float* p = P + ((size_t)b * n + i) * 3;
    const float px = p[0], py = p[1], pz = p[2];

    // search chunk: block-uniform addresses -> s_load_dwordx4
    const float4* __restrict__ q = pack + (dir == 0 ? 0 : (size_t)B * M) + (size_t)b * mm;
    const int chunk = mm / JC;
    const int j0 = blockIdx.y * chunk;

    float m0 = 3.4e38f, m1 = 3.4e38f, m2 = 3.4e38f, m3 = 3.4e38f;

    for (int j = j0; j < j0 + chunk; j += 8) {
        float4 q0 = q[j + 0], q1 = q[j + 1], q2 = q[j + 2], q3 = q[j + 3];
        float4 q4 = q[j + 4], q5 = q[j + 5], q6 = q[j + 6], q7 = q[j + 7];
        m0 = fminf(m0, fmaf(px, q0.x, fmaf(py, q0.y, fmaf(pz, q0.z, q0.w))));
        m1 = fminf(m1, fmaf(px, q1.x, fmaf(py, q1.y, fmaf(pz, q1.z, q1.w))));
        m2 = fminf(m2, fmaf(px, q2.x, fmaf(py, q2.y, fmaf(pz, q2.z, q2.w))));
        m3 = fminf(m3, fmaf(px, q3.x, fmaf(py, q3.y, fmaf(pz, q3.z, q3.w))));
        m0 = fminf(m0, fmaf(px, q4.x, fmaf(py, q4.y, fmaf(pz, q4.z, q4.w))));
        m1 = fminf(m1, fmaf(px, q5.x, fmaf(py, q5.y, fmaf(pz, q5.z, q5.w))));
        m2 = fminf(m2, fmaf(px, q6.x, fmaf(py, q6.y, fmaf(pz, q6.z, q6.w))));
        m3 = fminf(m3, fmaf(px, q7.x, fmaf(py, q7.y, fmaf(pz, q7.z, q7.w))));
    }

    float v = fminf(fminf(m0, m1), fminf(m2, m3)) + (px * px + py * py + pz * pz);

    // minws layout: [dir0: b*N+i][dir1: B*N + b*M+i]
    int* dst = minws + (dir == 0 ? (size_t)b * N + i : (size_t)B * N + (size_t)b * M + i);
    atomicMin(dst, __float_as_int(v));
}

// Phase 2: sum all mins with per-direction scale -> out[0]
__global__ __launch_bounds__(BLOCK) void reduce_kernel(
    const int* __restrict__ minws, float* __restrict__ out,
    int BN, int total, float scale1, float scale2)
{
    int t = blockIdx.x * BLOCK + threadIdx.x;
    float v = 0.f;
    if (t < total)
        v = __int_as_float(minws[t]) * (t < BN ? scale1 : scale2);

    #pragma unroll
    for (int off = 32; off > 0; off >>= 1)
        v += __shfl_down(v, off, 64);

    __shared__ float ssum[BLOCK / 64];
    const int lane = threadIdx.x & 63;
    const int wave = threadIdx.x >> 6;
    if (lane == 0) ssum[wave] = v;
    __syncthreads();

    if (threadIdx.x == 0) {
        float s = 0.f;
        #pragma unroll
        for (int w = 0; w < BLOCK / 64; ++w) s += ssum[w];
        atomicAdd(out, s);
    }
}

extern "C" void kernel_launch(void* const* d_in, const int* in_sizes, int n_in,
                              void* d_out, int out_size, void* d_ws, size_t ws_size,
                              hipStream_t stream) {
    const float* xyz1 = (const float*)d_in[0];
    const float* xyz2 = (const float*)d_in[1];
    float* out = (float*)d_out;

    const int B = 4;
    const int N = in_sizes[0] / (B * 3);   // 8192
    const int M = in_sizes[1] / (B * 3);   // 8192
    const int BN = B * N, BM = B * M;
    const int total = BN + BM;

    // ws layout: [pack: total float4][minws: total int]
    float4* pack  = (float4*)d_ws;
    int*    minws = (int*)(pack + total);

    // init: minws -> 0x7F7F7F7F (big positive float), out -> 0
    hipMemsetAsync(minws, 0x7F, sizeof(int) * (size_t)total, stream);
    hipMemsetAsync(out, 0, sizeof(float) * out_size, stream);

    pack_kernel<<<(total + BLOCK - 1) / BLOCK, BLOCK, 0, stream>>>(xyz1, xyz2, pack, BN, BM);

    dim3 grid(N / BLOCK, JC, 2 * B);
    chamfer_min_kernel<<<grid, BLOCK, 0, stream>>>(xyz1, xyz2, pack, minws, N, M, B);

    const float scale1 = 1.0f / (float)BN;
    const float scale2 = 1.0f / (float)BM;
    reduce_kernel<<<(total + BLOCK - 1) / BLOCK, BLOCK, 0, stream>>>(
        minws, out, BN, total, scale1, scale2);
}

// Round 3
// 120.311 us; speedup vs baseline: 3.2077x; 1.2316x over previous
//
#include <hip/hip_runtime.h>

#define BLOCK 256
#define JC 32         // j-chunks per (dir, b)
#define QPT 4         // queries per thread

// Phase 0: pack search sets as (-2x, -2y, -2z, |q|^2), init minws and out.
// pack[0 .. B*M)       = packed xyz2  (search set for dir 0)
// pack[B*M .. B*M+B*N) = packed xyz1  (search set for dir 1)
__global__ __launch_bounds__(BLOCK) void pack_init_kernel(
    const float* __restrict__ xyz1, const float* __restrict__ xyz2,
    float4* __restrict__ pack, int* __restrict__ minws, float* __restrict__ out,
    int BN, int BM)
{
    int t = blockIdx.x * BLOCK + threadIdx.x;
    if (t < BM) {
        float x = xyz2[3 * t], y = xyz2[3 * t + 1], z = xyz2[3 * t + 2];
        pack[t] = make_float4(-2.f * x, -2.f * y, -2.f * z, x * x + y * y + z * z);
    } else if (t < BM + BN) {
        int u = t - BM;
        float x = xyz1[3 * u], y = xyz1[3 * u + 1], z = xyz1[3 * u + 2];
        pack[t] = make_float4(-2.f * x, -2.f * y, -2.f * z, x * x + y * y + z * z);
    }
    if (t < BM + BN) minws[t] = 0x7F7F7F7F;   // big positive float
    if (t == 0) out[0] = 0.f;
}

// Phase 1: each thread owns QPT queries; loops over one chunk of the search
// set (block-uniform addresses -> s_load into SGPRs). Partial mins combined
// via atomicMin on int bits (positive-float int compare preserves order).
__global__ __launch_bounds__(BLOCK) void chamfer_min_kernel(
    const float* __restrict__ xyz1, const float* __restrict__ xyz2,
    const float4* __restrict__ pack, int* __restrict__ minws,
    int N, int M, int B)
{
    const int z   = blockIdx.z;        // dir*B + b
    const int dir = z >> 2;            // B == 4
    const int b   = z & 3;

    const float* __restrict__ P = (dir == 0) ? xyz1 : xyz2;  // queries
    const int n  = (dir == 0) ? N : M;                       // query count
    const int mm = (dir == 0) ? M : N;                       // search count

    // QPT queries per thread, coalesced within each k-slice
    const int ibase = blockIdx.x * (BLOCK * QPT) + threadIdx.x;

    float px[QPT], py[QPT], pz[QPT], mn[QPT];
    #pragma unroll
    for (int k = 0; k < QPT; ++k) {
        const int i = ibase + k * BLOCK;
        const float* p = P + ((size_t)b * n + i) * 3;
        px[k] = p[0]; py[k] = p[1]; pz[k] = p[2];
        mn[k] = 3.4e38f;
    }

    // search chunk: block-uniform -> scalar loads
    const float4* __restrict__ q = pack + (dir == 0 ? 0 : (size_t)B * M) + (size_t)b * mm;
    const int chunk = mm / JC;
    const int j0 = blockIdx.y * chunk;

    #pragma unroll 4
    for (int j = j0; j < j0 + chunk; ++j) {
        float4 qq = q[j];
        #pragma unroll
        for (int k = 0; k < QPT; ++k) {
            float d = fmaf(px[k], qq.x, fmaf(py[k], qq.y, fmaf(pz[k], qq.z, qq.w)));
            mn[k] = fminf(mn[k], d);
        }
    }

    // minws layout: [dir0: b*N+i][dir1: B*N + b*M+i]
    int* __restrict__ base = minws + (dir == 0 ? (size_t)b * N : (size_t)B * N + (size_t)b * M);
    #pragma unroll
    for (int k = 0; k < QPT; ++k) {
        const int i = ibase + k * BLOCK;
        float v = mn[k] + (px[k] * px[k] + py[k] * py[k] + pz[k] * pz[k]);
        atomicMin(base + i, __float_as_int(v));
    }
}

// Phase 2: sum all mins with per-direction scale -> out[0]
__global__ __launch_bounds__(BLOCK) void reduce_kernel(
    const int* __restrict__ minws, float* __restrict__ out,
    int BN, int total, float scale1, float scale2)
{
    int t = blockIdx.x * BLOCK + threadIdx.x;
    float v = 0.f;
    if (t < total)
        v = __int_as_float(minws[t]) * (t < BN ? scale1 : scale2);

    #pragma unroll
    for (int off = 32; off > 0; off >>= 1)
        v += __shfl_down(v, off, 64);

    __shared__ float ssum[BLOCK / 64];
    const int lane = threadIdx.x & 63;
    const int wave = threadIdx.x >> 6;
    if (lane == 0) ssum[wave] = v;
    __syncthreads();

    if (threadIdx.x == 0) {
        float s = 0.f;
        #pragma unroll
        for (int w = 0; w < BLOCK / 64; ++w) s += ssum[w];
        atomicAdd(out, s);
    }
}

extern "C" void kernel_launch(void* const* d_in, const int* in_sizes, int n_in,
                              void* d_out, int out_size, void* d_ws, size_t ws_size,
                              hipStream_t stream) {
    const float* xyz1 = (const float*)d_in[0];
    const float* xyz2 = (const float*)d_in[1];
    float* out = (float*)d_out;

    const int B = 4;
    const int N = in_sizes[0] / (B * 3);   // 8192
    const int M = in_sizes[1] / (B * 3);   // 8192
    const int BN = B * N, BM = B * M;
    const int total = BN + BM;

    // ws layout: [pack: total float4][minws: total int]
    float4* pack  = (float4*)d_ws;
    int*    minws = (int*)(pack + total);

    pack_init_kernel<<<(total + BLOCK - 1) / BLOCK, BLOCK, 0, stream>>>(
        xyz1, xyz2, pack, minws, out, BN, BM);

    dim3 grid(N / (BLOCK * QPT), JC, 2 * B);
    chamfer_min_kernel<<<grid, BLOCK, 0, stream>>>(xyz1, xyz2, pack, minws, N, M, B);

    const float scale1 = 1.0f / (float)BN;
    const float scale2 = 1.0f / (float)BM;
    reduce_kernel<<<(total + BLOCK - 1) / BLOCK, BLOCK, 0, stream>>>(
        minws, out, BN, total, scale1, scale2);
}

// Round 4
// 115.722 us; speedup vs baseline: 3.3349x; 1.0397x over previous
//
#include <hip/hip_runtime.h>

#define BLOCK 256
#define JC 64         // j-chunks per (dir, b): chunk = 8192/64 = 128 points
#define QPT 8         // queries per thread

// Phase 0: pack search sets as (-2x, -2y, -2z, |q|^2), init minws and out.
// pack[0 .. B*M)       = packed xyz2  (search set for dir 0)
// pack[B*M .. B*M+B*N) = packed xyz1  (search set for dir 1)
__global__ __launch_bounds__(BLOCK) void pack_init_kernel(
    const float* __restrict__ xyz1, const float* __restrict__ xyz2,
    float4* __restrict__ pack, int* __restrict__ minws, float* __restrict__ out,
    int BN, int BM)
{
    int t = blockIdx.x * BLOCK + threadIdx.x;
    if (t < BM) {
        float x = xyz2[3 * t], y = xyz2[3 * t + 1], z = xyz2[3 * t + 2];
        pack[t] = make_float4(-2.f * x, -2.f * y, -2.f * z, x * x + y * y + z * z);
    } else if (t < BM + BN) {
        int u = t - BM;
        float x = xyz1[3 * u], y = xyz1[3 * u + 1], z = xyz1[3 * u + 2];
        pack[t] = make_float4(-2.f * x, -2.f * y, -2.f * z, x * x + y * y + z * z);
    }
    if (t < BM + BN) minws[t] = 0x7F7F7F7F;   // big positive float
    if (t == 0) out[0] = 0.f;
}

// Phase 1: each thread owns QPT queries; loops over one 128-point chunk of
// the search set, 2 points per iteration, min3 pattern for the running min.
// Partial mins combined via atomicMin on int bits (positive floats: int
// compare preserves order).
__global__ __launch_bounds__(BLOCK) void chamfer_min_kernel(
    const float* __restrict__ xyz1, const float* __restrict__ xyz2,
    const float4* __restrict__ pack, int* __restrict__ minws,
    int N, int M, int B)
{
    const int z   = blockIdx.z;        // dir*B + b
    const int dir = z >> 2;            // B == 4
    const int b   = z & 3;

    const float* __restrict__ P = (dir == 0) ? xyz1 : xyz2;  // queries
    const int n  = (dir == 0) ? N : M;                       // query count
    const int mm = (dir == 0) ? M : N;                       // search count

    // QPT queries per thread, coalesced within each k-slice
    const int ibase = blockIdx.x * (BLOCK * QPT) + threadIdx.x;

    float px[QPT], py[QPT], pz[QPT], mn[QPT];
    #pragma unroll
    for (int k = 0; k < QPT; ++k) {
        const int i = ibase + k * BLOCK;
        const float* p = P + ((size_t)b * n + i) * 3;
        px[k] = p[0]; py[k] = p[1]; pz[k] = p[2];
        mn[k] = 3.4e38f;
    }

    // this block's search chunk
    const float4* __restrict__ q = pack + (dir == 0 ? 0 : (size_t)B * M) + (size_t)b * mm;
    const int chunk = mm / JC;
    const int j0 = blockIdx.y * chunk;

    #pragma unroll 2
    for (int j = j0; j < j0 + chunk; j += 2) {
        float4 qa = q[j], qb = q[j + 1];
        #pragma unroll
        for (int k = 0; k < QPT; ++k) {
            float d0 = fmaf(px[k], qa.x, fmaf(py[k], qa.y, fmaf(pz[k], qa.z, qa.w)));
            float d1 = fmaf(px[k], qb.x, fmaf(py[k], qb.y, fmaf(pz[k], qb.z, qb.w)));
            mn[k] = fminf(mn[k], fminf(d0, d1));   // -> v_min3_f32
        }
    }

    // minws layout: [dir0: b*N+i][dir1: B*N + b*M+i]
    int* __restrict__ base = minws + (dir == 0 ? (size_t)b * N : (size_t)B * N + (size_t)b * M);
    #pragma unroll
    for (int k = 0; k < QPT; ++k) {
        const int i = ibase + k * BLOCK;
        float v = mn[k] + (px[k] * px[k] + py[k] * py[k] + pz[k] * pz[k]);
        atomicMin(base + i, __float_as_int(v));
    }
}

// Phase 2: sum all mins with per-direction scale -> out[0]
__global__ __launch_bounds__(BLOCK) void reduce_kernel(
    const int* __restrict__ minws, float* __restrict__ out,
    int BN, int total, float scale1, float scale2)
{
    int t = blockIdx.x * BLOCK + threadIdx.x;
    float v = 0.f;
    if (t < total)
        v = __int_as_float(minws[t]) * (t < BN ? scale1 : scale2);

    #pragma unroll
    for (int off = 32; off > 0; off >>= 1)
        v += __shfl_down(v, off, 64);

    __shared__ float ssum[BLOCK / 64];
    const int lane = threadIdx.x & 63;
    const int wave = threadIdx.x >> 6;
    if (lane == 0) ssum[wave] = v;
    __syncthreads();

    if (threadIdx.x == 0) {
        float s = 0.f;
        #pragma unroll
        for (int w = 0; w < BLOCK / 64; ++w) s += ssum[w];
        atomicAdd(out, s);
    }
}

extern "C" void kernel_launch(void* const* d_in, const int* in_sizes, int n_in,
                              void* d_out, int out_size, void* d_ws, size_t ws_size,
                              hipStream_t stream) {
    const float* xyz1 = (const float*)d_in[0];
    const float* xyz2 = (const float*)d_in[1];
    float* out = (float*)d_out;

    const int B = 4;
    const int N = in_sizes[0] / (B * 3);   // 8192
    const int M = in_sizes[1] / (B * 3);   // 8192
    const int BN = B * N, BM = B * M;
    const int total = BN + BM;

    // ws layout: [pack: total float4][minws: total int]
    float4* pack  = (float4*)d_ws;
    int*    minws = (int*)(pack + total);

    pack_init_kernel<<<(total + BLOCK - 1) / BLOCK, BLOCK, 0, stream>>>(
        xyz1, xyz2, pack, minws, out, BN, BM);

    dim3 grid(N / (BLOCK * QPT), JC, 2 * B);
    chamfer_min_kernel<<<grid, BLOCK, 0, stream>>>(xyz1, xyz2, pack, minws, N, M, B);

    const float scale1 = 1.0f / (float)BN;
    const float scale2 = 1.0f / (float)BM;
    reduce_kernel<<<(total + BLOCK - 1) / BLOCK, BLOCK, 0, stream>>>(
        minws, out, BN, total, scale1, scale2);
}

// Round 5
// 90.720 us; speedup vs baseline: 4.2540x; 1.2756x over previous
//
#include <hip/hip_runtime.h>

typedef __attribute__((ext_vector_type(8))) short short8;
typedef __attribute__((ext_vector_type(16))) float f32x16;

#define NB 8192        // points per (batch, set); B=4
#define JT_REAL 256    // 32-point j-tiles per (set,b)
#define JT_PAD  258    // +2 pad tiles for prefetch (d = +3.4e38 there)
#define ONE_BF 0x3F80
#define BIG_BF 0x7F7F

__device__ inline unsigned short bf_rne(float f) {
    unsigned u = __float_as_uint(f);
    return (unsigned short)((u + 0x7fffu + ((u >> 16) & 1u)) >> 16);
}
__device__ inline float bf_up(unsigned short h) { return __uint_as_float(((unsigned)h) << 16); }

// Phase 0: build B-operand fragments (MFMA 32x32x16 lane order) for both
// search sets; init minws (0x7F7F7F7F) and out (0).
// K-slot content (half = lane>>5, n = lane&31, point q = jtile*32+n):
//   half0 k0..7 : [(-2qx)_hi,(-2qx)_lo,(-2qy)_hi,(-2qy)_lo,(-2qz)_hi,(-2qz)_lo,|q|2_hi,|q|2_lo]
//   half1 k8..15: [(-2qx)_hi,(-2qy)_hi,(-2qz)_hi, 1.0, 1.0, 0,0,0]
// Pad tiles: half0 slot6 = BIG (so d = 1.0*BIG, never the min).
__global__ __launch_bounds__(256) void pack_kernel(
    const float* __restrict__ xyz1, const float* __restrict__ xyz2,
    short8* __restrict__ bfrag, int* __restrict__ minws, float* __restrict__ out)
{
    int t = blockIdx.x * 256 + threadIdx.x;
    const int FRAGS = 8 * JT_PAD * 64;
    if (t < FRAGS) {
        int lane = t & 63;
        int jt   = (t >> 6) % JT_PAD;
        int sb   = t / (64 * JT_PAD);     // set*4 + b ; set0 = xyz2 (search for dir0)
        int set = sb >> 2, b = sb & 3;
        int n = lane & 31, half = lane >> 5;
        short8 v = {0, 0, 0, 0, 0, 0, 0, 0};
        if (jt >= JT_REAL) {
            if (half == 0) v[6] = (short)BIG_BF;
        } else {
            const float* src = (set == 0) ? xyz2 : xyz1;
            const float* q = src + ((size_t)b * NB + (size_t)jt * 32 + n) * 3;
            float x = q[0], y = q[1], z = q[2];
            float mx = -2.f * x, my = -2.f * y, mz = -2.f * z;
            float qsq = x * x + y * y + z * z;
            unsigned short mhx = bf_rne(mx), mhy = bf_rne(my), mhz = bf_rne(mz);
            if (half == 0) {
                unsigned short mlx = bf_rne(mx - bf_up(mhx));
                unsigned short mly = bf_rne(my - bf_up(mhy));
                unsigned short mlz = bf_rne(mz - bf_up(mhz));
                unsigned short qh  = bf_rne(qsq);
                unsigned short ql  = bf_rne(qsq - bf_up(qh));
                v[0] = (short)mhx; v[1] = (short)mlx;
                v[2] = (short)mhy; v[3] = (short)mly;
                v[4] = (short)mhz; v[5] = (short)mlz;
                v[6] = (short)qh;  v[7] = (short)ql;
            } else {
                v[0] = (short)mhx; v[1] = (short)mhy; v[2] = (short)mhz;
                v[3] = (short)ONE_BF; v[4] = (short)ONE_BF;
            }
        }
        bfrag[t] = v;
    }
    if (t < 2 * 4 * NB) minws[t] = 0x7F7F7F7F;
    if (t == 0) out[0] = 0.f;
}

// Phase 1: MFMA distance tiles + running min.
// Wave owns 128 rows (4 row-tiles of 32). A-operand built in-register:
//   half0 k0..7 : [px_hi,px_hi,py_hi,py_hi,pz_hi,pz_hi, 1.0, 1.0]
//   half1 k8..15: [px_lo,py_lo,pz_lo,|p|2_hi,|p|2_lo, 0,0,0]
// => D = -2p.q + |q|2 + |p|2 = d^2 directly (error ~1e-5 from dropped lo*lo).
__global__ __launch_bounds__(256, 2) void chamfer_mfma_kernel(
    const float* __restrict__ xyz1, const float* __restrict__ xyz2,
    const short8* __restrict__ bfrag, int* __restrict__ minws)
{
    const int z    = blockIdx.z;        // dir*4 + b
    const int dir  = z >> 2;
    const int b    = z & 3;
    const int lane = threadIdx.x & 63;
    const int w    = threadIdx.x >> 6;
    const int half = lane >> 5;
    const int m    = lane & 31;

    const float* __restrict__ P = (dir == 0) ? xyz1 : xyz2;   // query set

    const int rowbase = blockIdx.x * 512 + w * 128;
    short8 a[4];
    #pragma unroll
    for (int t = 0; t < 4; ++t) {
        const float* p = P + ((size_t)b * NB + rowbase + t * 32 + m) * 3;
        float x = p[0], y = p[1], zc = p[2];
        float psq = x * x + y * y + zc * zc;
        unsigned short hx = bf_rne(x), hy = bf_rne(y), hz = bf_rne(zc);
        short8 v = {0, 0, 0, 0, 0, 0, 0, 0};
        if (half == 0) {
            v[0] = (short)hx; v[1] = (short)hx;
            v[2] = (short)hy; v[3] = (short)hy;
            v[4] = (short)hz; v[5] = (short)hz;
            v[6] = (short)ONE_BF; v[7] = (short)ONE_BF;
        } else {
            unsigned short lx = bf_rne(x - bf_up(hx));
            unsigned short ly = bf_rne(y - bf_up(hy));
            unsigned short lz = bf_rne(zc - bf_up(hz));
            unsigned short ph = bf_rne(psq);
            unsigned short pl = bf_rne(psq - bf_up(ph));
            v[0] = (short)lx; v[1] = (short)ly; v[2] = (short)lz;
            v[3] = (short)ph; v[4] = (short)pl;
        }
        a[t] = v;
    }

    float rmn[4][16];
    #pragma unroll
    for (int t = 0; t < 4; ++t)
        #pragma unroll
        for (int r = 0; r < 16; ++r) rmn[t][r] = 3.4e38f;

    const f32x16 zero16 = {0,0,0,0,0,0,0,0,0,0,0,0,0,0,0,0};

    const short8* __restrict__ bp = bfrag + (size_t)z * JT_PAD * 64;
    const int j0 = blockIdx.y * (JT_REAL / 4);      // 64 tiles per j-chunk

    short8 f0 = bp[(size_t)(j0 + 0) * 64 + lane];
    short8 f1 = bp[(size_t)(j0 + 1) * 64 + lane];
    for (int jt = j0; jt < j0 + JT_REAL / 4; jt += 2) {
        short8 g0 = bp[(size_t)(jt + 2) * 64 + lane];
        short8 g1 = bp[(size_t)(jt + 3) * 64 + lane];
        #pragma unroll
        for (int t = 0; t < 4; ++t) {
            f32x16 d0 = __builtin_amdgcn_mfma_f32_32x32x16_bf16(a[t], f0, zero16, 0, 0, 0);
            f32x16 d1 = __builtin_amdgcn_mfma_f32_32x32x16_bf16(a[t], f1, zero16, 0, 0, 0);
            #pragma unroll
            for (int r = 0; r < 16; ++r)
                rmn[t][r] = fminf(rmn[t][r], fminf(d0[r], d1[r]));  // v_min3
        }
        f0 = g0; f1 = g1;
    }

    // min across the 32 lanes of each half (the j-columns)
    #pragma unroll
    for (int t = 0; t < 4; ++t)
        #pragma unroll
        for (int r = 0; r < 16; ++r) {
            float v = rmn[t][r];
            #pragma unroll
            for (int off = 16; off > 0; off >>= 1)
                v = fminf(v, __shfl_xor(v, off, 32));
            rmn[t][r] = v;
        }

    // C/D row mapping: row = (r&3) + 8*(r>>2) + 4*half  [m74/m101]
    int* __restrict__ base = minws + (dir == 0 ? (size_t)b * NB
                                               : (size_t)4 * NB + (size_t)b * NB);
    if (m == 0) {
        #pragma unroll
        for (int t = 0; t < 4; ++t)
            #pragma unroll
            for (int r = 0; r < 16; ++r) {
                int row = rowbase + t * 32 + 4 * half + (r & 3) + 8 * (r >> 2);
                atomicMin(base + row, __float_as_int(rmn[t][r]));
            }
    }
}

// Phase 2: sum all mins with per-direction scale -> out[0]
__global__ __launch_bounds__(256) void reduce_kernel(
    const int* __restrict__ minws, float* __restrict__ out,
    int BN, int total, float scale1, float scale2)
{
    int t = blockIdx.x * 256 + threadIdx.x;
    float v = 0.f;
    if (t < total)
        v = __int_as_float(minws[t]) * (t < BN ? scale1 : scale2);

    #pragma unroll
    for (int off = 32; off > 0; off >>= 1)
        v += __shfl_down(v, off, 64);

    __shared__ float ssum[4];
    const int lane = threadIdx.x & 63;
    const int wave = threadIdx.x >> 6;
    if (lane == 0) ssum[wave] = v;
    __syncthreads();

    if (threadIdx.x == 0) {
        float s = 0.f;
        #pragma unroll
        for (int wv = 0; wv < 4; ++wv) s += ssum[wv];
        atomicAdd(out, s);
    }
}

extern "C" void kernel_launch(void* const* d_in, const int* in_sizes, int n_in,
                              void* d_out, int out_size, void* d_ws, size_t ws_size,
                              hipStream_t stream) {
    const float* xyz1 = (const float*)d_in[0];
    const float* xyz2 = (const float*)d_in[1];
    float* out = (float*)d_out;

    const int B = 4;
    const int BN = B * NB, BM = B * NB;
    const int total = BN + BM;            // 65536

    // ws: [bfrag: 8*258*64 short8 = 2.06 MB][minws: 64K ints = 256 KB]
    short8* bfrag = (short8*)d_ws;
    int* minws = (int*)(bfrag + (size_t)8 * JT_PAD * 64);

    const int FRAGS = 8 * JT_PAD * 64;    // 132096 = 516*256 exactly
    pack_kernel<<<(FRAGS + 255) / 256, 256, 0, stream>>>(xyz1, xyz2, bfrag, minws, out);

    dim3 grid(16, 4, 2 * B);              // rows/512, j-splits, dir*B+b
    chamfer_mfma_kernel<<<grid, 256, 0, stream>>>(xyz1, xyz2, bfrag, minws);

    const float scale1 = 1.0f / (float)BN;
    const float scale2 = 1.0f / (float)BM;
    reduce_kernel<<<(total + 255) / 256, 256, 0, stream>>>(
        minws, out, BN, total, scale1, scale2);
}

// Round 6
// 87.377 us; speedup vs baseline: 4.4167x; 1.0383x over previous
//
#include <hip/hip_runtime.h>

typedef __attribute__((ext_vector_type(8))) short short8;
typedef __attribute__((ext_vector_type(16))) float f32x16;

#define NB 8192        // points per (batch, set); B=4
#define JT_REAL 256    // 32-point j-tiles per (set,b)
#define JT_PAD  258    // +2 pad tiles for prefetch overrun (d = +BIG there)
#define JC 4           // j-splits per (dir,b)
#define ONE_BF 0x3F80
#define BIG_BF 0x7F7F

__device__ inline unsigned short bf_rne(float f) {
    unsigned u = __float_as_uint(f);
    return (unsigned short)((u + 0x7fffu + ((u >> 16) & 1u)) >> 16);
}
__device__ inline float bf_up(unsigned short h) { return __uint_as_float(((unsigned)h) << 16); }

// Phase 0: build B-operand fragments (MFMA 32x32x16 lane order) for both
// search sets; init minws (0x7F7F7F7F) and out (0).
// K-slot content (half = lane>>5, n = lane&31, point q = jtile*32+n):
//   half0 k0..7 : [(-2qx)_hi,(-2qx)_lo,(-2qy)_hi,(-2qy)_lo,(-2qz)_hi,(-2qz)_lo,|q|2_hi,|q|2_lo]
//   half1 k8..15: [(-2qx)_hi,(-2qy)_hi,(-2qz)_hi, 1.0, 1.0, 0,0,0]
// Pad tiles: half0 slot6 = BIG (so d = 1.0*BIG, never the min).
__global__ __launch_bounds__(256) void pack_kernel(
    const float* __restrict__ xyz1, const float* __restrict__ xyz2,
    short8* __restrict__ bfrag, int* __restrict__ minws, float* __restrict__ out)
{
    int t = blockIdx.x * 256 + threadIdx.x;
    const int FRAGS = 8 * JT_PAD * 64;
    if (t < FRAGS) {
        int lane = t & 63;
        int jt   = (t >> 6) % JT_PAD;
        int sb   = t / (64 * JT_PAD);     // set*4 + b ; set0 = xyz2 (search for dir0)
        int set = sb >> 2, b = sb & 3;
        int n = lane & 31, half = lane >> 5;
        short8 v = {0, 0, 0, 0, 0, 0, 0, 0};
        if (jt >= JT_REAL) {
            if (half == 0) v[6] = (short)BIG_BF;
        } else {
            const float* src = (set == 0) ? xyz2 : xyz1;
            const float* q = src + ((size_t)b * NB + (size_t)jt * 32 + n) * 3;
            float x = q[0], y = q[1], z = q[2];
            float mx = -2.f * x, my = -2.f * y, mz = -2.f * z;
            float qsq = x * x + y * y + z * z;
            unsigned short mhx = bf_rne(mx), mhy = bf_rne(my), mhz = bf_rne(mz);
            if (half == 0) {
                unsigned short mlx = bf_rne(mx - bf_up(mhx));
                unsigned short mly = bf_rne(my - bf_up(mhy));
                unsigned short mlz = bf_rne(mz - bf_up(mhz));
                unsigned short qh  = bf_rne(qsq);
                unsigned short ql  = bf_rne(qsq - bf_up(qh));
                v[0] = (short)mhx; v[1] = (short)mlx;
                v[2] = (short)mhy; v[3] = (short)mly;
                v[4] = (short)mhz; v[5] = (short)mlz;
                v[6] = (short)qh;  v[7] = (short)ql;
            } else {
                v[0] = (short)mhx; v[1] = (short)mhy; v[2] = (short)mhz;
                v[3] = (short)ONE_BF; v[4] = (short)ONE_BF;
            }
        }
        bfrag[t] = v;
    }
    if (t < 2 * 4 * NB) minws[t] = 0x7F7F7F7F;
    if (t == 0) out[0] = 0.f;
}

// Phase 1: MFMA distance tiles + running min.
// Wave owns 64 rows (2 row-tiles of 32). A-operand built in-register:
//   half0 k0..7 : [px_hi,px_hi,py_hi,py_hi,pz_hi,pz_hi, 1.0, 1.0]
//   half1 k8..15: [px_lo,py_lo,pz_lo,|p|2_hi,|p|2_lo, 0,0,0]
// => D = -2p.q + |q|2 + |p|2 = d^2 directly (error ~1e-5 from dropped lo*lo).
// Grid (32, JC, 8) = 1024 blocks = 4 blocks/CU; launch_bounds(256,4) caps
// VGPR at 128 -> 4 waves/SIMD, one clean dispatch round.
__global__ __launch_bounds__(256, 4) void chamfer_mfma_kernel(
    const float* __restrict__ xyz1, const float* __restrict__ xyz2,
    const short8* __restrict__ bfrag, int* __restrict__ minws)
{
    const int z    = blockIdx.z;        // dir*4 + b
    const int dir  = z >> 2;
    const int b    = z & 3;
    const int lane = threadIdx.x & 63;
    const int w    = threadIdx.x >> 6;
    const int half = lane >> 5;
    const int m    = lane & 31;

    const float* __restrict__ P = (dir == 0) ? xyz1 : xyz2;   // query set

    const int rowbase = blockIdx.x * 256 + w * 64;
    short8 a[2];
    #pragma unroll
    for (int t = 0; t < 2; ++t) {
        const float* p = P + ((size_t)b * NB + rowbase + t * 32 + m) * 3;
        float x = p[0], y = p[1], zc = p[2];
        float psq = x * x + y * y + zc * zc;
        unsigned short hx = bf_rne(x), hy = bf_rne(y), hz = bf_rne(zc);
        short8 v = {0, 0, 0, 0, 0, 0, 0, 0};
        if (half == 0) {
            v[0] = (short)hx; v[1] = (short)hx;
            v[2] = (short)hy; v[3] = (short)hy;
            v[4] = (short)hz; v[5] = (short)hz;
            v[6] = (short)ONE_BF; v[7] = (short)ONE_BF;
        } else {
            unsigned short lx = bf_rne(x - bf_up(hx));
            unsigned short ly = bf_rne(y - bf_up(hy));
            unsigned short lz = bf_rne(zc - bf_up(hz));
            unsigned short ph = bf_rne(psq);
            unsigned short pl = bf_rne(psq - bf_up(ph));
            v[0] = (short)lx; v[1] = (short)ly; v[2] = (short)lz;
            v[3] = (short)ph; v[4] = (short)pl;
        }
        a[t] = v;
    }

    float rmn[2][16];
    #pragma unroll
    for (int t = 0; t < 2; ++t)
        #pragma unroll
        for (int r = 0; r < 16; ++r) rmn[t][r] = 3.4e38f;

    const f32x16 zero16 = {0,0,0,0,0,0,0,0,0,0,0,0,0,0,0,0};

    const short8* __restrict__ bp = bfrag + (size_t)z * JT_PAD * 64;
    const int j0 = blockIdx.y * (JT_REAL / JC);     // 64 tiles per j-chunk

    short8 f0 = bp[(size_t)(j0 + 0) * 64 + lane];
    short8 f1 = bp[(size_t)(j0 + 1) * 64 + lane];
    for (int jt = j0; jt < j0 + JT_REAL / JC; jt += 2) {
        short8 g0 = bp[(size_t)(jt + 2) * 64 + lane];
        short8 g1 = bp[(size_t)(jt + 3) * 64 + lane];
        #pragma unroll
        for (int t = 0; t < 2; ++t) {
            f32x16 d0 = __builtin_amdgcn_mfma_f32_32x32x16_bf16(a[t], f0, zero16, 0, 0, 0);
            f32x16 d1 = __builtin_amdgcn_mfma_f32_32x32x16_bf16(a[t], f1, zero16, 0, 0, 0);
            #pragma unroll
            for (int r = 0; r < 16; ++r)
                rmn[t][r] = fminf(rmn[t][r], fminf(d0[r], d1[r]));  // v_min3
        }
        f0 = g0; f1 = g1;
    }

    // min across the 32 lanes of each half (the j-columns)
    #pragma unroll
    for (int t = 0; t < 2; ++t)
        #pragma unroll
        for (int r = 0; r < 16; ++r) {
            float v = rmn[t][r];
            #pragma unroll
            for (int off = 16; off > 0; off >>= 1)
                v = fminf(v, __shfl_xor(v, off, 32));
            rmn[t][r] = v;
        }

    // C/D row mapping: row = (r&3) + 8*(r>>2) + 4*half  [m74/m101]
    int* __restrict__ base = minws + (dir == 0 ? (size_t)b * NB
                                               : (size_t)4 * NB + (size_t)b * NB);
    if (m == 0) {
        #pragma unroll
        for (int t = 0; t < 2; ++t)
            #pragma unroll
            for (int r = 0; r < 16; ++r) {
                int row = rowbase + t * 32 + 4 * half + (r & 3) + 8 * (r >> 2);
                atomicMin(base + row, __float_as_int(rmn[t][r]));
            }
    }
}

// Phase 2: sum all mins with per-direction scale -> out[0]
__global__ __launch_bounds__(256) void reduce_kernel(
    const int* __restrict__ minws, float* __restrict__ out,
    int BN, int total, float scale1, float scale2)
{
    int t = blockIdx.x * 256 + threadIdx.x;
    float v = 0.f;
    if (t < total)
        v = __int_as_float(minws[t]) * (t < BN ? scale1 : scale2);

    #pragma unroll
    for (int off = 32; off > 0; off >>= 1)
        v += __shfl_down(v, off, 64);

    __shared__ float ssum[4];
    const int lane = threadIdx.x & 63;
    const int wave = threadIdx.x >> 6;
    if (lane == 0) ssum[wave] = v;
    __syncthreads();

    if (threadIdx.x == 0) {
        float s = 0.f;
        #pragma unroll
        for (int wv = 0; wv < 4; ++wv) s += ssum[wv];
        atomicAdd(out, s);
    }
}

extern "C" void kernel_launch(void* const* d_in, const int* in_sizes, int n_in,
                              void* d_out, int out_size, void* d_ws, size_t ws_size,
                              hipStream_t stream) {
    const float* xyz1 = (const float*)d_in[0];
    const float* xyz2 = (const float*)d_in[1];
    float* out = (float*)d_out;

    const int B = 4;
    const int BN = B * NB, BM = B * NB;
    const int total = BN + BM;            // 65536

    // ws: [bfrag: 8*258*64 short8 = 2.06 MB][minws: 64K ints = 256 KB]
    short8* bfrag = (short8*)d_ws;
    int* minws = (int*)(bfrag + (size_t)8 * JT_PAD * 64);

    const int FRAGS = 8 * JT_PAD * 64;    // 132096 = 516*256 exactly
    pack_kernel<<<(FRAGS + 255) / 256, 256, 0, stream>>>(xyz1, xyz2, bfrag, minws, out);

    dim3 grid(32, JC, 2 * B);             // rows/256, j-splits, dir*B+b
    chamfer_mfma_kernel<<<grid, 256, 0, stream>>>(xyz1, xyz2, bfrag, minws);

    const float scale1 = 1.0f / (float)BN;
    const float scale2 = 1.0f / (float)BM;
    reduce_kernel<<<(total + 255) / 256, 256, 0, stream>>>(
        minws, out, BN, total, scale1, scale2);
}